// Round 2
// baseline (521.875 us; speedup 1.0000x reference)
//
#include <hip/hip_runtime.h>

#define BATCH   2048
#define NFIELDS 40
#define EMB     64
#define PAIRS   780
#define BM      128
#define NTILES  (BATCH / BM)          // 16
#define NBLOCKS (PAIRS * NTILES)      // 12480

typedef __attribute__((ext_vector_type(8))) short          short8;
typedef __attribute__((ext_vector_type(8))) unsigned short ushort8;
typedef __attribute__((ext_vector_type(4))) float          fvec4;

__device__ __forceinline__ unsigned short f2bf(float f) {
    unsigned int x = __float_as_uint(f);
    return (unsigned short)((x + 0x7fffu + ((x >> 16) & 1u)) >> 16);  // RTNE
}
__device__ __forceinline__ float bf2f(unsigned short h) {
    return __uint_as_float(((unsigned int)h) << 16);
}

// out[b][p][e] = (sum_d femb[b][lp][d] * W[p][d][e]) * femb[b][rp][e]
// fp32 via 3-term bf16 split: a*w ~= ah*wh + ah*wl + al*wh  (err ~2^-16)
__global__ __launch_bounds__(256, 2) void bilinear_kernel(
    const float* __restrict__ femb, const float* __restrict__ W,
    const int* __restrict__ lidx, const int* __restrict__ ridx,
    float* __restrict__ out)
{
    // W transposed: Wt[e][k]; L tile: L[row][k]. hi/lo bf16, XOR-swizzled
    // in 8-element (16B) chunks: chunk' = chunk ^ (row&7) breaks the
    // 16-way bank conflict of 128B-stride rows on ds_read_b128.
    __shared__ unsigned short Wh[64 * 64];
    __shared__ unsigned short Wl[64 * 64];
    __shared__ unsigned short Lh[BM * 64];
    __shared__ unsigned short Ll[BM * 64];

    // Bijective XCD swizzle (12480 % 8 == 0): XCD r owns a contiguous
    // p-range -> its W slice (~1.6MB) fits the per-XCD 4MB L2.
    int d   = blockIdx.x;
    int w   = (d & 7) * (NBLOCKS / 8) + (d >> 3);
    int p   = w >> 4;       // w / NTILES
    int b0  = (w & 15) * BM;

    int lp = lidx[p];
    int rp = ridx[p];
    int t  = threadIdx.x;

    // ---- stage W[p] -> Wt[e][k] hi/lo (transpose; col-reads are coalesced
    //      across lanes since consecutive lanes take consecutive e) ----
    {
        const float* Wp = W + (size_t)p * (EMB * EMB);
        int e  = t & 63;
        int k0 = (t >> 6) * 16;
        #pragma unroll
        for (int c2 = 0; c2 < 2; ++c2) {
            ushort8 hi, lo;
            int kb = k0 + c2 * 8;
            #pragma unroll
            for (int i = 0; i < 8; ++i) {
                float f = Wp[(size_t)(kb + i) * EMB + e];
                unsigned short h = f2bf(f);
                hi[i] = h;
                lo[i] = f2bf(f - bf2f(h));
            }
            int chunk = kb >> 3;
            int dst   = e * 64 + ((chunk ^ (e & 7)) << 3);
            *(ushort8*)&Wh[dst] = hi;
            *(ushort8*)&Wl[dst] = lo;
        }
    }
    // ---- stage L tile: rows b0..b0+127 of field lp ----
    {
        int row = t >> 1;
        int k0  = (t & 1) * 32;
        const float* Lr = femb + ((size_t)(b0 + row) * NFIELDS + lp) * EMB + k0;
        #pragma unroll
        for (int c2 = 0; c2 < 4; ++c2) {
            fvec4 fa = *(const fvec4*)&Lr[c2 * 8];
            fvec4 fb = *(const fvec4*)&Lr[c2 * 8 + 4];
            ushort8 hi, lo;
            #pragma unroll
            for (int i = 0; i < 4; ++i) {
                unsigned short h = f2bf(fa[i]);
                hi[i] = h; lo[i] = f2bf(fa[i] - bf2f(h));
                unsigned short h2 = f2bf(fb[i]);
                hi[i + 4] = h2; lo[i + 4] = f2bf(fb[i] - bf2f(h2));
            }
            int chunk = (k0 >> 3) + c2;
            int dst   = row * 64 + ((chunk ^ (row & 7)) << 3);
            *(ushort8*)&Lh[dst] = hi;
            *(ushort8*)&Ll[dst] = lo;
        }
    }
    __syncthreads();

    // ---- MFMA: wave wv owns rows [wv*32, wv*32+32) x all 64 cols ----
    int wv   = t >> 6;
    int l    = t & 63;
    int lrow = l & 15;   // A row / B col / D col within 16-tile
    int lgrp = l >> 4;   // k-group (A/B), row-group (D)

    fvec4 acc[2][4] = {};
    #pragma unroll
    for (int kk = 0; kk < 2; ++kk) {
        int kbase = kk * 32 + lgrp * 8;
        int chunk = kbase >> 3;
        short8 Ah[2], Al[2];
        #pragma unroll
        for (int m = 0; m < 2; ++m) {
            int r   = wv * 32 + m * 16 + lrow;
            int src = r * 64 + ((chunk ^ (r & 7)) << 3);
            Ah[m] = *(short8*)&Lh[src];
            Al[m] = *(short8*)&Ll[src];
        }
        #pragma unroll
        for (int n = 0; n < 4; ++n) {
            int e   = n * 16 + lrow;
            int src = e * 64 + ((chunk ^ (e & 7)) << 3);
            short8 Bh = *(short8*)&Wh[src];
            short8 Bl = *(short8*)&Wl[src];
            #pragma unroll
            for (int m = 0; m < 2; ++m) {
                acc[m][n] = __builtin_amdgcn_mfma_f32_16x16x32_bf16(Al[m], Bh, acc[m][n], 0, 0, 0);
                acc[m][n] = __builtin_amdgcn_mfma_f32_16x16x32_bf16(Ah[m], Bl, acc[m][n], 0, 0, 0);
                acc[m][n] = __builtin_amdgcn_mfma_f32_16x16x32_bf16(Ah[m], Bh, acc[m][n], 0, 0, 0);
            }
        }
    }

    // ---- epilogue: gate by R (no reuse -> straight global loads), store.
    // D layout (verified m89/m91): col = lane&15, row = (lane>>4)*4 + reg.
    #pragma unroll
    for (int m = 0; m < 2; ++m) {
        int rb = b0 + wv * 32 + m * 16 + lgrp * 4;
        #pragma unroll
        for (int r = 0; r < 4; ++r) {
            int b = rb + r;
            const float* Rr = femb + ((size_t)b * NFIELDS + rp) * EMB;
            float*       Or = out  + ((size_t)b * PAIRS   + p)  * EMB;
            #pragma unroll
            for (int n = 0; n < 4; ++n) {
                int col = n * 16 + lrow;
                Or[col] = acc[m][n][r] * Rr[col];
            }
        }
    }
}

extern "C" void kernel_launch(void* const* d_in, const int* in_sizes, int n_in,
                              void* d_out, int out_size, void* d_ws, size_t ws_size,
                              hipStream_t stream) {
    const float* femb = (const float*)d_in[0];
    const float* W    = (const float*)d_in[1];
    const int*   lidx = (const int*)d_in[2];
    const int*   ridx = (const int*)d_in[3];
    float*       out  = (float*)d_out;
    bilinear_kernel<<<NBLOCKS, 256, 0, stream>>>(femb, W, lidx, ridx, out);
}